// Round 11
// baseline (146.055 us; speedup 1.0000x reference)
//
#include <hip/hip_runtime.h>

#define N_NODES 8192
#define N_EDGES 8192
#define DEG 32
#define D 32
#define CAP 128   // fixed CSR slots per node (Poisson(32); P(deg>128) ~ 0)

typedef float vf4 __attribute__((ext_vector_type(4)));

// Algebra (full collapse):
//   M = Wm1@Wm2@Wm3 (64x1), split M0 (node half) / M1 (edge half);
//   c = bm1@(Wm2@Wm3) + bm2@Wm3 + bm3
//   w2u = Wl2@M0 ;  v_y = Wl1@w2u ;  v_z = Wl1@M1
//   A1[e]  = sum_{unique n in e} x0[n]
//   B1[n]  = sum_{e in CSR[n]} A1[e] ;  y[n] = B1·v_y ; z[n] = B1·v_z
//   qw[e]  = sum_{n' in e} y[n'] ;  q[e] = sum_{n' in e} z[n']
//   p[n]   = c + sum_{e in CSR[n]} qw[e]
//   out[n,e] = p[n] + q[e] at incidence nonzeros, else 0.

// ---------------------------------------------------------------------------
// K1: block 0 folds weights into consts; all blocks: edge-agg1
// (dedup mask + CSR fill + A1). 8 edges/block, 32 lanes/edge.
// ---------------------------------------------------------------------------
__global__ void __launch_bounds__(256)
k1_edge(const float* __restrict__ x0, const float* __restrict__ Wl1,
        const float* __restrict__ Wl2, const float* __restrict__ Wm1,
        const float* __restrict__ bm1, const float* __restrict__ Wm2,
        const float* __restrict__ bm2, const float* __restrict__ Wm3,
        const float* __restrict__ bm3, const int* __restrict__ node_idx,
        float* __restrict__ A, unsigned* __restrict__ validmask,
        int* __restrict__ cursor, int* __restrict__ csr_e,
        float* __restrict__ consts) {
    __shared__ int sidx[8][32];
    __shared__ unsigned smask[8];
    __shared__ float fsh[128];
    const int t = threadIdx.x, el = t >> 5, s = t & 31;

    if (blockIdx.x == 0) {
        float* w23 = fsh;        // 32
        float* M0  = fsh + 32;   // 32
        float* M1  = fsh + 64;   // 32
        float* w2u = fsh + 96;   // 32
        if (t < 32) {
            float acc = 0.f;
            for (int k = 0; k < 32; ++k) acc += Wm2[t * 32 + k] * Wm3[k];
            w23[t] = acc;
        }
        __syncthreads();
        if (t < 64) {
            float acc = 0.f;
            for (int k = 0; k < 32; ++k) acc += Wm1[t * 32 + k] * w23[k];
            if (t < 32) M0[t] = acc; else M1[t - 32] = acc;
        }
        if (t == 0) {
            float c = bm3[0];
            for (int k = 0; k < 32; ++k) c += bm1[k] * w23[k] + bm2[k] * Wm3[k];
            consts[0] = c;
        }
        __syncthreads();
        if (t < 32) {
            float acc = 0.f;
            for (int d2 = 0; d2 < 32; ++d2) acc += Wl2[t * 32 + d2] * M0[d2];
            w2u[t] = acc;
        }
        __syncthreads();
        if (t < 32) {
            float ay = 0.f, az = 0.f;
            for (int d2 = 0; d2 < 32; ++d2) {
                float w = Wl1[t * 32 + d2];
                ay += w * w2u[d2];
                az += w * M1[d2];
            }
            consts[1 + t]  = ay;   // v_y
            consts[33 + t] = az;   // v_z
        }
        __syncthreads();
    }

    // ---- edge-agg1 ----
    int e = blockIdx.x * 8 + el;
    int idx = node_idx[e * DEG + s];
    sidx[el][s] = idx;
    __syncthreads();
    bool valid = true;
    for (int j = 0; j < s; ++j)
        if (sidx[el][j] == idx) { valid = false; break; }
    unsigned long long bl = __ballot(valid);
    if (s == 0) {
        unsigned m = (unsigned)(bl >> (t & 32));
        smask[el] = m;
        validmask[e] = m;
    }
    if (valid) {
        int pos = atomicAdd(&cursor[idx], 1);
        if (pos < CAP) csr_e[idx * CAP + pos] = e;
    }
    __syncthreads();
    unsigned m = smask[el];
    float acc = 0.f;
#pragma unroll
    for (int j = 0; j < 32; ++j)
        if ((m >> j) & 1u) acc += x0[sidx[el][j] * D + s];
    A[e * D + s] = acc;
}

// ---------------------------------------------------------------------------
// K2a: per node, B1 = sum of A1 rows in CSR[n]; y[n] = B1·v_y, z[n] = B1·v_z.
// 8 nodes/block, 32 lanes/node. Coalesced gathers, no atomics.
// ---------------------------------------------------------------------------
__global__ void __launch_bounds__(256)
k2_node(const float* __restrict__ A, const int* __restrict__ csr_e,
        const int* __restrict__ cursor, const float* __restrict__ consts,
        float* __restrict__ y, float* __restrict__ z) {
    const int t = threadIdx.x, el = t >> 5, s = t & 31;
    int n = blockIdx.x * 8 + el;
    int cnt = min(cursor[n], CAP);
    const int* lst = csr_e + n * CAP;
    float acc = 0.f;
    int j = 0;
    for (; j + 4 <= cnt; j += 4) {
        int4 e4 = *(const int4*)(lst + j);
        acc += A[e4.x * D + s] + A[e4.y * D + s] +
               A[e4.z * D + s] + A[e4.w * D + s];
    }
    for (; j < cnt; ++j) acc += A[lst[j] * D + s];
    float ay = acc * consts[1 + s];
    float az = acc * consts[33 + s];
#pragma unroll
    for (int off = 16; off; off >>= 1) {
        ay += __shfl_xor(ay, off);
        az += __shfl_xor(az, off);
    }
    if (s == 0) { y[n] = ay; z[n] = az; }
}

// ---------------------------------------------------------------------------
// K2b: per edge, qw[e] = sum of y over valid member nodes; q[e] = same for z.
// 8 edges/block, 32 lanes/edge; y/z tables are 32 KB (L1/L2-hot).
// ---------------------------------------------------------------------------
__global__ void __launch_bounds__(256)
k2_edge(const int* __restrict__ node_idx, const unsigned* __restrict__ validmask,
        const float* __restrict__ y, const float* __restrict__ z,
        float* __restrict__ qw, float* __restrict__ q) {
    const int t = threadIdx.x, el = t >> 5, s = t & 31;
    int e = blockIdx.x * 8 + el;
    unsigned m = validmask[e];
    int idx = node_idx[e * DEG + s];
    bool valid = (m >> s) & 1u;
    float ay = valid ? y[idx] : 0.f;
    float az = valid ? z[idx] : 0.f;
#pragma unroll
    for (int off = 16; off; off >>= 1) {
        ay += __shfl_xor(ay, off);
        az += __shfl_xor(az, off);
    }
    if (s == 0) { qw[e] = ay; q[e] = az; }
}

// ---------------------------------------------------------------------------
// K3: one block per output row, NO dense LDS row. 1 KB LDS bitmap (8192 bits)
// + (eid,val) arrays; each thread composes its 8 float4 chunks on the fly:
// zero unless the chunk's 4-bit nibble is set (~1.5% of chunks), then a
// <=cnt linear scan supplies the patch value. LDS ~2 KB -> 8 blocks/CU
// (vs 5 with the 32 KB row image): deeper write pipelining.
// ---------------------------------------------------------------------------
__global__ void __launch_bounds__(256)
k3_out(const int* __restrict__ csr_e, const int* __restrict__ cursor,
       const float* __restrict__ qw, const float* __restrict__ q,
       const float* __restrict__ consts, float* __restrict__ out) {
    __shared__ unsigned bmap[256];   // 8192 bits, one per column
    __shared__ float val[CAP];
    __shared__ int eid[CAP];
    __shared__ float sp;
    const int t = threadIdx.x;
    const int n = blockIdx.x;
    const int cnt = min(cursor[n], CAP);
    bmap[t & 255] = 0;
    if (t < CAP) eid[t] = csr_e[n * CAP + t];
    __syncthreads();
    // p[n] = c + sum qw[eid]
    if (t < 32) {
        float v = 0.f;
        for (int j = t; j < cnt; j += 32) v += qw[eid[j]];
#pragma unroll
        for (int off = 16; off; off >>= 1) v += __shfl_xor(v, off);
        if (t == 0) sp = v + consts[0];
    }
    __syncthreads();
    float pn = sp;
    if (t < cnt) {
        int e = eid[t];
        val[t] = pn + q[e];
        atomicOr(&bmap[e >> 5], 1u << (e & 31));
    }
    __syncthreads();
    vf4* g4 = (vf4*)(out + (size_t)n * N_EDGES);
#pragma unroll
    for (int k = 0; k < 8; ++k) {
        int i = t + 256 * k;                    // chunk: columns [4i, 4i+4)
        unsigned nib = (bmap[i >> 3] >> ((i & 7) * 4)) & 0xFu;
        vf4 v = (vf4)(0.f);
        if (nib) {
#pragma unroll
            for (int b = 0; b < 4; ++b) {
                if ((nib >> b) & 1u) {
                    int col = 4 * i + b;
                    for (int j = 0; j < cnt; ++j)
                        if (eid[j] == col) { v[b] = val[j]; break; }
                }
            }
        }
        g4[i] = v;
    }
}

extern "C" void kernel_launch(void* const* d_in, const int* in_sizes, int n_in,
                              void* d_out, int out_size, void* d_ws, size_t ws_size,
                              hipStream_t stream) {
    const float* x0  = (const float*)d_in[0];
    // d_in[1] = dense incidence matrix: unused (sparse path).
    const float* Wl1 = (const float*)d_in[2];
    const float* Wl2 = (const float*)d_in[3];
    const float* Wm1 = (const float*)d_in[4];
    const float* bm1 = (const float*)d_in[5];
    const float* Wm2 = (const float*)d_in[6];
    const float* bm2 = (const float*)d_in[7];
    const float* Wm3 = (const float*)d_in[8];
    const float* bm3 = (const float*)d_in[9];
    const int* node_idx = (const int*)d_in[10];
    float* out = (float*)d_out;

    // Workspace layout
    char* ws = (char*)d_ws;
    int*      cursor    = (int*)(ws);                          // 32 KB
    float*    y         = (float*)(ws + ( 32u << 10));         // 32 KB
    float*    z         = (float*)(ws + ( 64u << 10));         // 32 KB
    unsigned* validmask = (unsigned*)(ws + ( 96u << 10));      // 32 KB
    float*    qw        = (float*)(ws + (128u << 10));         // 32 KB
    float*    q         = (float*)(ws + (160u << 10));         // 32 KB
    float*    consts    = (float*)(ws + (192u << 10));         // 65 floats
    float*    A         = (float*)(ws + (1u << 20));           // 1 MB [E*D]
    int*      csr_e     = (int*)(ws + (2u << 20));             // 4 MB [N*CAP]

    hipMemsetAsync(cursor, 0, N_NODES * sizeof(int), stream);
    k1_edge<<<N_EDGES / 8, 256, 0, stream>>>(x0, Wl1, Wl2, Wm1, bm1, Wm2, bm2,
                                             Wm3, bm3, node_idx, A, validmask,
                                             cursor, csr_e, consts);
    k2_node<<<N_NODES / 8, 256, 0, stream>>>(A, csr_e, cursor, consts, y, z);
    k2_edge<<<N_EDGES / 8, 256, 0, stream>>>(node_idx, validmask, y, z, qw, q);
    k3_out<<<N_NODES, 256, 0, stream>>>(csr_e, cursor, qw, q, consts, out);
}

// Round 12
// 81.861 us; speedup vs baseline: 1.7842x; 1.7842x over previous
//
#include <hip/hip_runtime.h>

#define N_NODES 8192
#define N_EDGES 8192
#define DEG 32
#define D 32
#define CAP 128   // fixed CSR slots per node (Poisson(32); P(deg>128) ~ 0)
#define HALF 4096 // columns per k3 block (half a row)

typedef float vf4 __attribute__((ext_vector_type(4)));

// Algebra (full collapse):
//   M = Wm1@Wm2@Wm3 (64x1), split M0 (node half) / M1 (edge half);
//   c = bm1@(Wm2@Wm3) + bm2@Wm3 + bm3
//   w2u = Wl2@M0 ;  v_y = Wl1@w2u ;  v_z = Wl1@M1
//   A1[e]  = sum_{unique n in e} x0[n]
//   B1[n]  = sum_{e in CSR[n]} A1[e] ;  y[n] = B1·v_y ; z[n] = B1·v_z
//   qw[e]  = sum_{n' in e} y[n'] ;  q[e] = sum_{n' in e} z[n']
//   p[n]   = c + sum_{e in CSR[n]} qw[e]
//   out[n,e] = p[n] + q[e] at incidence nonzeros, else 0.

// ---------------------------------------------------------------------------
// K1: block 0 folds weights into consts; all blocks: edge-agg1
// (dedup mask + CSR fill + A1). 8 edges/block, 32 lanes/edge.
// ---------------------------------------------------------------------------
__global__ void __launch_bounds__(256)
k1_edge(const float* __restrict__ x0, const float* __restrict__ Wl1,
        const float* __restrict__ Wl2, const float* __restrict__ Wm1,
        const float* __restrict__ bm1, const float* __restrict__ Wm2,
        const float* __restrict__ bm2, const float* __restrict__ Wm3,
        const float* __restrict__ bm3, const int* __restrict__ node_idx,
        float* __restrict__ A, unsigned* __restrict__ validmask,
        int* __restrict__ cursor, int* __restrict__ csr_e,
        float* __restrict__ consts) {
    __shared__ int sidx[8][32];
    __shared__ unsigned smask[8];
    __shared__ float fsh[128];
    const int t = threadIdx.x, el = t >> 5, s = t & 31;

    if (blockIdx.x == 0) {
        float* w23 = fsh;        // 32
        float* M0  = fsh + 32;   // 32
        float* M1  = fsh + 64;   // 32
        float* w2u = fsh + 96;   // 32
        if (t < 32) {
            float acc = 0.f;
            for (int k = 0; k < 32; ++k) acc += Wm2[t * 32 + k] * Wm3[k];
            w23[t] = acc;
        }
        __syncthreads();
        if (t < 64) {
            float acc = 0.f;
            for (int k = 0; k < 32; ++k) acc += Wm1[t * 32 + k] * w23[k];
            if (t < 32) M0[t] = acc; else M1[t - 32] = acc;
        }
        if (t == 0) {
            float c = bm3[0];
            for (int k = 0; k < 32; ++k) c += bm1[k] * w23[k] + bm2[k] * Wm3[k];
            consts[0] = c;
        }
        __syncthreads();
        if (t < 32) {
            float acc = 0.f;
            for (int d2 = 0; d2 < 32; ++d2) acc += Wl2[t * 32 + d2] * M0[d2];
            w2u[t] = acc;
        }
        __syncthreads();
        if (t < 32) {
            float ay = 0.f, az = 0.f;
            for (int d2 = 0; d2 < 32; ++d2) {
                float w = Wl1[t * 32 + d2];
                ay += w * w2u[d2];
                az += w * M1[d2];
            }
            consts[1 + t]  = ay;   // v_y
            consts[33 + t] = az;   // v_z
        }
        __syncthreads();
    }

    // ---- edge-agg1 ----
    int e = blockIdx.x * 8 + el;
    int idx = node_idx[e * DEG + s];
    sidx[el][s] = idx;
    __syncthreads();
    bool valid = true;
    for (int j = 0; j < s; ++j)
        if (sidx[el][j] == idx) { valid = false; break; }
    unsigned long long bl = __ballot(valid);
    if (s == 0) {
        unsigned m = (unsigned)(bl >> (t & 32));
        smask[el] = m;
        validmask[e] = m;
    }
    if (valid) {
        int pos = atomicAdd(&cursor[idx], 1);
        if (pos < CAP) csr_e[idx * CAP + pos] = e;
    }
    __syncthreads();
    unsigned m = smask[el];
    float acc = 0.f;
#pragma unroll
    for (int j = 0; j < 32; ++j)
        if ((m >> j) & 1u) acc += x0[sidx[el][j] * D + s];
    A[e * D + s] = acc;
}

// ---------------------------------------------------------------------------
// K2a: per node, B1 = sum of A1 rows in CSR[n]; y[n] = B1·v_y, z[n] = B1·v_z.
// 8 nodes/block, 32 lanes/node. Coalesced gathers, no atomics.
// ---------------------------------------------------------------------------
__global__ void __launch_bounds__(256)
k2_node(const float* __restrict__ A, const int* __restrict__ csr_e,
        const int* __restrict__ cursor, const float* __restrict__ consts,
        float* __restrict__ y, float* __restrict__ z) {
    const int t = threadIdx.x, el = t >> 5, s = t & 31;
    int n = blockIdx.x * 8 + el;
    int cnt = min(cursor[n], CAP);
    const int* lst = csr_e + n * CAP;
    float acc = 0.f;
    int j = 0;
    for (; j + 4 <= cnt; j += 4) {
        int4 e4 = *(const int4*)(lst + j);
        acc += A[e4.x * D + s] + A[e4.y * D + s] +
               A[e4.z * D + s] + A[e4.w * D + s];
    }
    for (; j < cnt; ++j) acc += A[lst[j] * D + s];
    float ay = acc * consts[1 + s];
    float az = acc * consts[33 + s];
#pragma unroll
    for (int off = 16; off; off >>= 1) {
        ay += __shfl_xor(ay, off);
        az += __shfl_xor(az, off);
    }
    if (s == 0) { y[n] = ay; z[n] = az; }
}

// ---------------------------------------------------------------------------
// K2b: per edge, qw[e] = sum of y over valid member nodes; q[e] = same for z.
// 8 edges/block, 32 lanes/edge; y/z tables are 32 KB (L1/L2-hot).
// ---------------------------------------------------------------------------
__global__ void __launch_bounds__(256)
k2_edge(const int* __restrict__ node_idx, const unsigned* __restrict__ validmask,
        const float* __restrict__ y, const float* __restrict__ z,
        float* __restrict__ qw, float* __restrict__ q) {
    const int t = threadIdx.x, el = t >> 5, s = t & 31;
    int e = blockIdx.x * 8 + el;
    unsigned m = validmask[e];
    int idx = node_idx[e * DEG + s];
    bool valid = (m >> s) & 1u;
    float ay = valid ? y[idx] : 0.f;
    float az = valid ? z[idx] : 0.f;
#pragma unroll
    for (int off = 16; off; off >>= 1) {
        ay += __shfl_xor(ay, off);
        az += __shfl_xor(az, off);
    }
    if (s == 0) { qw[e] = ay; q[e] = az; }
}

// ---------------------------------------------------------------------------
// K3: two blocks per output row (16 KB half-row in LDS each). Branch-free
// dense compose (R10 structure) but at 8 blocks/CU (wave-limited 100%
// occupancy) instead of 5: zero LDS half-row, p = c + sum qw[eid], patch
// in-range cells with p + q[eid], stream 16 KB out with float4 writes.
// ---------------------------------------------------------------------------
__global__ void __launch_bounds__(256)
k3_out(const int* __restrict__ csr_e, const int* __restrict__ cursor,
       const float* __restrict__ qw, const float* __restrict__ q,
       const float* __restrict__ consts, float* __restrict__ out) {
    __shared__ float row[HALF];   // 16 KB half-row
    __shared__ int eid[CAP];
    __shared__ float sp;
    const int t = threadIdx.x;
    const int n = blockIdx.x >> 1;
    const int h = blockIdx.x & 1;          // which half of the row
    const int base = h * HALF;
    const int cnt = min(cursor[n], CAP);
    if (t < CAP) eid[t] = csr_e[n * CAP + t];
    vf4* r4 = (vf4*)row;
    vf4 zz = (vf4)(0.f);
#pragma unroll
    for (int k = 0; k < 4; ++k) r4[t + 256 * k] = zz;
    __syncthreads();
    // p[n] = c + sum qw[eid]  (full sum; duplicated across both halves)
    if (t < 32) {
        float v = 0.f;
        for (int j = t; j < cnt; j += 32) v += qw[eid[j]];
#pragma unroll
        for (int off = 16; off; off >>= 1) v += __shfl_xor(v, off);
        if (t == 0) sp = v + consts[0];
    }
    __syncthreads();
    float pn = sp;
    for (int j = t; j < cnt; j += 256) {
        int e = eid[j];
        int le = e - base;
        if ((unsigned)le < (unsigned)HALF) row[le] = pn + q[e];
    }
    __syncthreads();
    vf4* g4 = (vf4*)(out + (size_t)n * N_EDGES + base);
#pragma unroll
    for (int k = 0; k < 4; ++k) g4[t + 256 * k] = r4[t + 256 * k];
}

extern "C" void kernel_launch(void* const* d_in, const int* in_sizes, int n_in,
                              void* d_out, int out_size, void* d_ws, size_t ws_size,
                              hipStream_t stream) {
    const float* x0  = (const float*)d_in[0];
    // d_in[1] = dense incidence matrix: unused (sparse path).
    const float* Wl1 = (const float*)d_in[2];
    const float* Wl2 = (const float*)d_in[3];
    const float* Wm1 = (const float*)d_in[4];
    const float* bm1 = (const float*)d_in[5];
    const float* Wm2 = (const float*)d_in[6];
    const float* bm2 = (const float*)d_in[7];
    const float* Wm3 = (const float*)d_in[8];
    const float* bm3 = (const float*)d_in[9];
    const int* node_idx = (const int*)d_in[10];
    float* out = (float*)d_out;

    // Workspace layout
    char* ws = (char*)d_ws;
    int*      cursor    = (int*)(ws);                          // 32 KB
    float*    y         = (float*)(ws + ( 32u << 10));         // 32 KB
    float*    z         = (float*)(ws + ( 64u << 10));         // 32 KB
    unsigned* validmask = (unsigned*)(ws + ( 96u << 10));      // 32 KB
    float*    qw        = (float*)(ws + (128u << 10));         // 32 KB
    float*    q         = (float*)(ws + (160u << 10));         // 32 KB
    float*    consts    = (float*)(ws + (192u << 10));         // 65 floats
    float*    A         = (float*)(ws + (1u << 20));           // 1 MB [E*D]
    int*      csr_e     = (int*)(ws + (2u << 20));             // 4 MB [N*CAP]

    hipMemsetAsync(cursor, 0, N_NODES * sizeof(int), stream);
    k1_edge<<<N_EDGES / 8, 256, 0, stream>>>(x0, Wl1, Wl2, Wm1, bm1, Wm2, bm2,
                                             Wm3, bm3, node_idx, A, validmask,
                                             cursor, csr_e, consts);
    k2_node<<<N_NODES / 8, 256, 0, stream>>>(A, csr_e, cursor, consts, y, z);
    k2_edge<<<N_EDGES / 8, 256, 0, stream>>>(node_idx, validmask, y, z, qw, q);
    k3_out<<<2 * N_NODES, 256, 0, stream>>>(csr_e, cursor, qw, q, consts, out);
}